// Round 15
// baseline (162.675 us; speedup 1.0000x reference)
//
#include <hip/hip_runtime.h>

// Fused double-softmax attention, fp32 in/out, f16 MFMA for QK^T and PV.
// B=4 H=8 S=1024 D=64. Outputs: context [B,H,S,D] then attn [B,H,S,S].
// R15 = R13 (best valid: NT streams, 36KB LDS, batched per-row Phase-B loads)
//       + s_setprio(1) around MFMA clusters (T5: cross-block phase diversity).
typedef _Float16 f16;
typedef _Float16 f16x8 __attribute__((ext_vector_type(8)));
typedef _Float16 f16x4 __attribute__((ext_vector_type(4)));
typedef float f32x4 __attribute__((ext_vector_type(4)));
typedef int   i32x4 __attribute__((ext_vector_type(4)));

constexpr int B_ = 4, H_ = 8, S_ = 1024, D_ = 64;
constexpr int BQ = 16;        // q rows per block
constexpr int NT = 512;       // 8 waves
constexpr int KC = 128;       // k per chunk (one 16-col tile per wave)
constexpr int QH_LD = 72;     // Qh row stride in f16
constexpr int SC_LD = 1032;   // sch row stride in f16
constexpr float LOG2E = 1.44269504f;

__device__ __forceinline__ float wred(float v) {
#pragma unroll
  for (int off = 32; off > 0; off >>= 1) v += __shfl_xor(v, off);
  return v;
}

__global__ __launch_bounds__(NT)
void fused_attn(const float* __restrict__ Q, const float* __restrict__ K,
                const float* __restrict__ V, const int* __restrict__ mask,
                const float* __restrict__ adj, const float* __restrict__ dist,
                const float* __restrict__ cw, const float* __restrict__ cb,
                float* __restrict__ outC, float* __restrict__ outA)
{
  __shared__ __align__(16) f16 Qh[BQ * QH_LD];     // 2.3 KB
  __shared__ __align__(16) f16 sch[BQ * SC_LD];    // 33.0 KB (C-scratch reuse)
  __shared__ float rs1w[8][16];
  __shared__ float rinv2[BQ];

  const int tid = threadIdx.x;
  // bijective XCD swizzle: 2048 blocks = 8 XCDs x 256 (4 heads per XCD)
  const int sw = (blockIdx.x & 7) * 256 + (blockIdx.x >> 3);
  const int qt = sw & 63;
  const int bh = sw >> 6;
  const int q0 = qt * BQ;
  const int wv = tid >> 6;    // wave 0..7
  const int ln = tid & 63;
  const int lg = ln >> 4;     // lane group 0..3
  const int li = ln & 15;

  const float* Qp = Q + ((size_t)bh * S_ + q0) * D_;
  const float* Kp = K + (size_t)bh * S_ * D_;
  const float* Vp = V + (size_t)bh * S_ * D_;
  const size_t rb = ((size_t)bh * S_ + q0) * S_;

  // stage Q tile -> f16
  if (tid < 256) {
    const int q = tid >> 4, c4 = (tid & 15) << 2;
    float4 v = *(const float4*)(Qp + q * D_ + c4);
    f16* d = &Qh[q * QH_LD + c4];
    d[0] = (f16)v.x; d[1] = (f16)v.y; d[2] = (f16)v.z; d[3] = (f16)v.w;
  }
  const float w0 = cw[0], w1 = cw[1], w2 = cw[2], bb = cb[0];
  __syncthreads();                                  // (1)

  // hoist Q fragments (A operand; lane li = q-row li, k = s*32 + lg*8)
  f16x8 aq0 = *(const f16x8*)&Qh[li * QH_LD + 0 * 32 + lg * 8];
  f16x8 aq1 = *(const f16x8*)&Qh[li * QH_LD + 1 * 32 + lg * 8];

  // ===== Phase A: UNMASKED e = exp(QK^T/8) via MFMA; K straight from global ==
  const int n0 = wv * 16;
  float rs[4] = {0.f, 0.f, 0.f, 0.f};
#pragma unroll 2
  for (int c = 0; c < 8; ++c) {
    const int kg = c * KC + n0 + li;
    const float* Kr = Kp + (size_t)kg * D_ + lg * 8;
    const float4 ka = *(const float4*)(Kr + 0);
    const float4 kb = *(const float4*)(Kr + 4);
    const float4 kc2 = *(const float4*)(Kr + 32);
    const float4 kd = *(const float4*)(Kr + 36);
    f16x8 b0, b1;
    b0[0] = (f16)ka.x; b0[1] = (f16)ka.y; b0[2] = (f16)ka.z; b0[3] = (f16)ka.w;
    b0[4] = (f16)kb.x; b0[5] = (f16)kb.y; b0[6] = (f16)kb.z; b0[7] = (f16)kb.w;
    b1[0] = (f16)kc2.x; b1[1] = (f16)kc2.y; b1[2] = (f16)kc2.z; b1[3] = (f16)kc2.w;
    b1[4] = (f16)kd.x; b1[5] = (f16)kd.y; b1[6] = (f16)kd.z; b1[7] = (f16)kd.w;
    __builtin_amdgcn_s_setprio(1);
    f32x4 acc = {0.f, 0.f, 0.f, 0.f};
    acc = __builtin_amdgcn_mfma_f32_16x16x32_f16(aq0, b0, acc, 0, 0, 0);
    acc = __builtin_amdgcn_mfma_f32_16x16x32_f16(aq1, b1, acc, 0, 0, 0);
    __builtin_amdgcn_s_setprio(0);
#pragma unroll
    for (int r = 0; r < 4; ++r) {            // D[m][n]: m=lg*4+r, n=li
      const int m = lg * 4 + r;
      const f16 ef = (f16)exp2f(acc[r] * (0.125f * LOG2E));
      sch[m * SC_LD + kg] = ef;
      rs[r] += (float)ef;                    // rounded full-row sum
    }
  }
#pragma unroll
  for (int r = 0; r < 4; ++r) {              // reduce over 16 lanes per group
    rs[r] += __shfl_xor(rs[r], 1); rs[r] += __shfl_xor(rs[r], 2);
    rs[r] += __shfl_xor(rs[r], 4); rs[r] += __shfl_xor(rs[r], 8);
  }
  if (li == 0) {
#pragma unroll
    for (int r = 0; r < 4; ++r) rs1w[wv][lg * 4 + r] = rs[r];
  }
  __syncthreads();                                  // (2) sch + rs1w visible

  // ===== Phase B: mask fold + conv-softmax; wave -> rows 2wv, 2wv+1 ==========
#pragma unroll
  for (int rr = 0; rr < 2; ++rr) {
    const int q = 2 * wv + rr;
    const size_t base = rb + (size_t)q * S_;
    const int k0 = ln * 4;
    // batched NONTEMPORAL loads: 12 global + 4 LDS issued before any use
    const i32x4 mv0 = __builtin_nontemporal_load((const i32x4*)(mask + base + k0 + 0));
    const i32x4 mv1 = __builtin_nontemporal_load((const i32x4*)(mask + base + k0 + 256));
    const i32x4 mv2 = __builtin_nontemporal_load((const i32x4*)(mask + base + k0 + 512));
    const i32x4 mv3 = __builtin_nontemporal_load((const i32x4*)(mask + base + k0 + 768));
    const f32x4 dv0 = __builtin_nontemporal_load((const f32x4*)(dist + base + k0 + 0));
    const f32x4 dv1 = __builtin_nontemporal_load((const f32x4*)(dist + base + k0 + 256));
    const f32x4 dv2 = __builtin_nontemporal_load((const f32x4*)(dist + base + k0 + 512));
    const f32x4 dv3 = __builtin_nontemporal_load((const f32x4*)(dist + base + k0 + 768));
    const f32x4 av0 = __builtin_nontemporal_load((const f32x4*)(adj + base + k0 + 0));
    const f32x4 av1 = __builtin_nontemporal_load((const f32x4*)(adj + base + k0 + 256));
    const f32x4 av2 = __builtin_nontemporal_load((const f32x4*)(adj + base + k0 + 512));
    const f32x4 av3 = __builtin_nontemporal_load((const f32x4*)(adj + base + k0 + 768));
    const f16x4 ef0 = *(const f16x4*)&sch[q * SC_LD + k0 + 0];
    const f16x4 ef1 = *(const f16x4*)&sch[q * SC_LD + k0 + 256];
    const f16x4 ef2 = *(const f16x4*)&sch[q * SC_LD + k0 + 512];
    const f16x4 ef3 = *(const f16x4*)&sch[q * SC_LD + k0 + 768];
    __builtin_amdgcn_sched_barrier(0);
    // denominator correction from masked entries
    float corr =
        (mv0[0] ? (float)ef0[0] : 0.f) + (mv0[1] ? (float)ef0[1] : 0.f) +
        (mv0[2] ? (float)ef0[2] : 0.f) + (mv0[3] ? (float)ef0[3] : 0.f) +
        (mv1[0] ? (float)ef1[0] : 0.f) + (mv1[1] ? (float)ef1[1] : 0.f) +
        (mv1[2] ? (float)ef1[2] : 0.f) + (mv1[3] ? (float)ef1[3] : 0.f) +
        (mv2[0] ? (float)ef2[0] : 0.f) + (mv2[1] ? (float)ef2[1] : 0.f) +
        (mv2[2] ? (float)ef2[2] : 0.f) + (mv2[3] ? (float)ef2[3] : 0.f) +
        (mv3[0] ? (float)ef3[0] : 0.f) + (mv3[1] ? (float)ef3[1] : 0.f) +
        (mv3[2] ? (float)ef3[2] : 0.f) + (mv3[3] ? (float)ef3[3] : 0.f);
    float tq = 0.f;
#pragma unroll
    for (int w = 0; w < 8; ++w) tq += rs1w[w][q];   // uniform broadcast reads
    corr = wred(corr);
    const float i1 = 1.f / (tq - corr);
    const float W0 = w0 * i1 * LOG2E, W1 = w1 * LOG2E, W2 = w2 * LOG2E;
    const float BBL = bb * LOG2E;
    f16x4 af0, af1, af2, af3;
    float s2 = 0.f;
#define CSM(AF, MV, DV, AV, EF)                                               \
    {                                                                         \
      const float t0 = fmaf(W0, (float)EF[0], fmaf(W1, DV[0], fmaf(W2, AV[0], BBL))); \
      const float t1 = fmaf(W0, (float)EF[1], fmaf(W1, DV[1], fmaf(W2, AV[1], BBL))); \
      const float t2 = fmaf(W0, (float)EF[2], fmaf(W1, DV[2], fmaf(W2, AV[2], BBL))); \
      const float t3 = fmaf(W0, (float)EF[3], fmaf(W1, DV[3], fmaf(W2, AV[3], BBL))); \
      const float a0 = MV[0] ? 0.f : exp2f(t0);                               \
      const float a1 = MV[1] ? 0.f : exp2f(t1);                               \
      const float a2 = MV[2] ? 0.f : exp2f(t2);                               \
      const float a3 = MV[3] ? 0.f : exp2f(t3);                               \
      AF[0] = (f16)a0; AF[1] = (f16)a1; AF[2] = (f16)a2; AF[3] = (f16)a3;     \
      s2 += a0 + a1 + a2 + a3;                                                \
    }
    CSM(af0, mv0, dv0, av0, ef0)
    CSM(af1, mv1, dv1, av1, ef1)
    CSM(af2, mv2, dv2, av2, ef2)
    CSM(af3, mv3, dv3, av3, ef3)
#undef CSM
    *(f16x4*)&sch[q * SC_LD + k0 + 0]   = af0;
    *(f16x4*)&sch[q * SC_LD + k0 + 256] = af1;
    *(f16x4*)&sch[q * SC_LD + k0 + 512] = af2;
    *(f16x4*)&sch[q * SC_LD + k0 + 768] = af3;
    s2 = wred(s2);
    const float i2 = 1.f / s2;
    if (ln == 0) rinv2[q] = i2;
    f32x4 o;
    o[0] = (float)af0[0] * i2; o[1] = (float)af0[1] * i2;
    o[2] = (float)af0[2] * i2; o[3] = (float)af0[3] * i2;
    __builtin_nontemporal_store(o, (f32x4*)(outA + base + k0 + 0));
    o[0] = (float)af1[0] * i2; o[1] = (float)af1[1] * i2;
    o[2] = (float)af1[2] * i2; o[3] = (float)af1[3] * i2;
    __builtin_nontemporal_store(o, (f32x4*)(outA + base + k0 + 256));
    o[0] = (float)af2[0] * i2; o[1] = (float)af2[1] * i2;
    o[2] = (float)af2[2] * i2; o[3] = (float)af2[3] * i2;
    __builtin_nontemporal_store(o, (f32x4*)(outA + base + k0 + 512));
    o[0] = (float)af3[0] * i2; o[1] = (float)af3[1] * i2;
    o[2] = (float)af3[2] * i2; o[3] = (float)af3[3] * i2;
    __builtin_nontemporal_store(o, (f32x4*)(outA + base + k0 + 768));
  }
  __syncthreads();                                  // (3) sch aw-values visible

  // ===== Phase C: ctx = P(f16) x V(f16); V^T fragments straight from global ==
  const int ntile = wv >> 1;
  const int spair = (wv & 1) * 2;
  const int d0 = ntile * 16 + li;
  f32x4 cacc = {0.f, 0.f, 0.f, 0.f};
#pragma unroll 2
  for (int c = 0; c < 8; ++c) {
#pragma unroll
    for (int u = 0; u < 2; ++u) {
      const int s = spair + u;
      const float* Vc = Vp + (size_t)(c * KC + s * 32 + lg * 8) * D_ + d0;
      f16x8 bfr;
#pragma unroll
      for (int j = 0; j < 8; ++j) bfr[j] = (f16)Vc[(size_t)j * D_];
      f16x8 a = *(const f16x8*)&sch[li * SC_LD + c * KC + s * 32 + lg * 8];
      __builtin_amdgcn_s_setprio(1);
      cacc = __builtin_amdgcn_mfma_f32_16x16x32_f16(a, bfr, cacc, 0, 0, 0);
      __builtin_amdgcn_s_setprio(0);
    }
  }
  __syncthreads();                                  // (4) all sch reads done
  float* fscr = reinterpret_cast<float*>(sch);      // alias 8 KB scratch
  *(f32x4*)&fscr[tid * 4] = cacc;
  __syncthreads();                                  // (5)
  if (tid < 256) {                    // combine wave pairs, scale, write ctx
    const int t = tid >> 6, l2 = tid & 63;
    const int g2 = l2 >> 4, n = l2 & 15;
    f32x4 p  = *(const f32x4*)&fscr[((2 * t) * 64 + l2) * 4];
    f32x4 p2 = *(const f32x4*)&fscr[((2 * t + 1) * 64 + l2) * 4];
#pragma unroll
    for (int r = 0; r < 4; ++r) {
      const int m = g2 * 4 + r;
      outC[((size_t)bh * S_ + q0 + m) * D_ + t * 16 + n] = (p[r] + p2[r]) * rinv2[m];
    }
  }
}

extern "C" void kernel_launch(void* const* d_in, const int* in_sizes, int n_in,
                              void* d_out, int out_size, void* d_ws, size_t ws_size,
                              hipStream_t stream) {
  const float* Q    = (const float*)d_in[0];
  const float* K    = (const float*)d_in[1];
  const float* V    = (const float*)d_in[2];
  const int*   mask = (const int*)  d_in[3];
  const float* adj  = (const float*)d_in[4];
  const float* dist = (const float*)d_in[5];
  const float* cw   = (const float*)d_in[6];
  const float* cb   = (const float*)d_in[7];

  float* outC = (float*)d_out;                                   // [B,H,S,D]
  float* outA = outC + (size_t)B_ * H_ * S_ * D_;                // [B,H,S,S]

  fused_attn<<<dim3(B_ * H_ * (S_ / BQ)), NT, 0, stream>>>(
      Q, K, V, mask, adj, dist, cw, cb, outC, outA);
}

// Round 16
// 153.240 us; speedup vs baseline: 1.0616x; 1.0616x over previous
//
#include <hip/hip_runtime.h>

// Fused double-softmax attention, fp32 in/out, f16 MFMA for QK^T and PV.
// B=4 H=8 S=1024 D=64. Outputs: context [B,H,S,D] then attn [B,H,S,S].
// R16: Phase-B HBM reads moved INTO Phase A as LDS staging -- per chunk c,
// rows 2c,2c+1 of mask/dist/adj are streamed (nontemporal) and reduced to
// comb = LOG2E*(w1*dist+w2*adj+b) f16 (masked -> -1e4 sentinel). Phase B is
// then pure LDS+VALU. Sentinel kills the corr/rs1w machinery. LDS = exactly
// 64 KB (sch 32K XOR-swizzled + comb 32K; Qh dropped -> Q frags from global;
// fscr/rinv aliased after Phase C). No setprio (R15 regressed).
typedef _Float16 f16;
typedef _Float16 f16x8 __attribute__((ext_vector_type(8)));
typedef _Float16 f16x4 __attribute__((ext_vector_type(4)));
typedef float f32x4 __attribute__((ext_vector_type(4)));
typedef int   i32x4 __attribute__((ext_vector_type(4)));

constexpr int B_ = 4, H_ = 8, S_ = 1024, D_ = 64;
constexpr int BQ = 16;        // q rows per block
constexpr int NT = 512;       // 8 waves
constexpr int KC = 128;       // k per chunk (one 16-col tile per wave)
constexpr float LOG2E = 1.44269504f;

__device__ __forceinline__ float wred(float v) {
#pragma unroll
  for (int off = 32; off > 0; off >>= 1) v += __shfl_xor(v, off);
  return v;
}

// sch f16-index swizzle: row-major [16][1024], idx ^ ((row&7)<<3).
// A-writes (scalar), B-r/w (f16x4), C-reads (f16x8) all stay aligned;
// C's 16-lane row-column read spreads over 8 bank groups (2-way = free).
__device__ __forceinline__ int swz(int row, int col) {
  return (row * 1024 + col) ^ ((row & 7) << 3);
}

__global__ __launch_bounds__(NT)
void fused_attn(const float* __restrict__ Q, const float* __restrict__ K,
                const float* __restrict__ V, const int* __restrict__ mask,
                const float* __restrict__ adj, const float* __restrict__ dist,
                const float* __restrict__ cw, const float* __restrict__ cb,
                float* __restrict__ outC, float* __restrict__ outA)
{
  __shared__ __align__(16) f16 sch[BQ * 1024];     // 32 KB (ef -> aw; fscr alias)
  __shared__ __align__(16) f16 comb[BQ * 1024];    // 32 KB (rinv alias)

  const int tid = threadIdx.x;
  // bijective XCD swizzle: 2048 blocks = 8 XCDs x 256 (4 heads per XCD)
  const int sw = (blockIdx.x & 7) * 256 + (blockIdx.x >> 3);
  const int qt = sw & 63;
  const int bh = sw >> 6;
  const int q0 = qt * BQ;
  const int wv = tid >> 6;    // wave 0..7
  const int ln = tid & 63;
  const int lg = ln >> 4;     // lane group 0..3
  const int li = ln & 15;

  const float* Qp = Q + ((size_t)bh * S_ + q0) * D_;
  const float* Kp = K + (size_t)bh * S_ * D_;
  const float* Vp = V + (size_t)bh * S_ * D_;
  const size_t rb = ((size_t)bh * S_ + q0) * S_;

  const float w0 = cw[0], w1 = cw[1], w2 = cw[2], bb = cb[0];
  const float W1 = w1 * LOG2E, W2 = w2 * LOG2E, BBL = bb * LOG2E;

  // Q fragments straight from global (L1/L2 broadcast across the 8 waves)
  f16x8 aq0, aq1;
  {
    const float* Qr = Qp + li * D_ + lg * 8;
    const float4 qa = *(const float4*)(Qr + 0);
    const float4 qb = *(const float4*)(Qr + 4);
    const float4 qc = *(const float4*)(Qr + 32);
    const float4 qd = *(const float4*)(Qr + 36);
    aq0[0] = (f16)qa.x; aq0[1] = (f16)qa.y; aq0[2] = (f16)qa.z; aq0[3] = (f16)qa.w;
    aq0[4] = (f16)qb.x; aq0[5] = (f16)qb.y; aq0[6] = (f16)qb.z; aq0[7] = (f16)qb.w;
    aq1[0] = (f16)qc.x; aq1[1] = (f16)qc.y; aq1[2] = (f16)qc.z; aq1[3] = (f16)qc.w;
    aq1[4] = (f16)qd.x; aq1[5] = (f16)qd.y; aq1[6] = (f16)qd.z; aq1[7] = (f16)qd.w;
  }

  // ===== Phase A: ef = exp(QK^T/8) via MFMA + stream-staging of comb ========
  const int n0 = wv * 16;
  const int srow = tid >> 8;            // 0/1: which of the chunk's 2 rows
  const int sk4 = (tid & 255) << 2;     // k quad within row
#pragma unroll 2
  for (int c = 0; c < 8; ++c) {
    // stream loads for rows 2c, 2c+1 (independent of MFMA; overlap it)
    const int row = 2 * c + srow;
    const size_t sb = rb + (size_t)row * S_ + sk4;
    const i32x4 mv = __builtin_nontemporal_load((const i32x4*)(mask + sb));
    const f32x4 dv = __builtin_nontemporal_load((const f32x4*)(dist + sb));
    const f32x4 av = __builtin_nontemporal_load((const f32x4*)(adj + sb));
    // K fragment + MFMA
    const int kg = c * KC + n0 + li;
    const float* Kr = Kp + (size_t)kg * D_ + lg * 8;
    const float4 ka = *(const float4*)(Kr + 0);
    const float4 kb = *(const float4*)(Kr + 4);
    const float4 kc2 = *(const float4*)(Kr + 32);
    const float4 kd = *(const float4*)(Kr + 36);
    f16x8 b0, b1;
    b0[0] = (f16)ka.x; b0[1] = (f16)ka.y; b0[2] = (f16)ka.z; b0[3] = (f16)ka.w;
    b0[4] = (f16)kb.x; b0[5] = (f16)kb.y; b0[6] = (f16)kb.z; b0[7] = (f16)kb.w;
    b1[0] = (f16)kc2.x; b1[1] = (f16)kc2.y; b1[2] = (f16)kc2.z; b1[3] = (f16)kc2.w;
    b1[4] = (f16)kd.x; b1[5] = (f16)kd.y; b1[6] = (f16)kd.z; b1[7] = (f16)kd.w;
    f32x4 acc = {0.f, 0.f, 0.f, 0.f};
    acc = __builtin_amdgcn_mfma_f32_16x16x32_f16(aq0, b0, acc, 0, 0, 0);
    acc = __builtin_amdgcn_mfma_f32_16x16x32_f16(aq1, b1, acc, 0, 0, 0);
    // comb pack + LDS store (masked -> -1e4: exp2 underflows to exact 0)
    f16x4 cbv;
#pragma unroll
    for (int j = 0; j < 4; ++j) {
      const float t = fmaf(W1, dv[j], fmaf(W2, av[j], BBL));
      cbv[j] = mv[j] ? (f16)(-10000.f) : (f16)t;
    }
    *(f16x4*)&comb[row * 1024 + sk4] = cbv;
    // ef -> sch (swizzled)
#pragma unroll
    for (int r = 0; r < 4; ++r) {            // D[m][n]: m=lg*4+r, n=li
      const int m = lg * 4 + r;
      sch[swz(m, kg)] = (f16)exp2f(acc[r] * (0.125f * LOG2E));
    }
  }
  __syncthreads();                                  // (1) sch ef + comb visible

  // ===== Phase B: pure LDS+VALU; wave -> rows 2wv, 2wv+1 =====================
  float i2q0, i2q1;
#define PHASEB(QV, I2OUT)                                                     \
  {                                                                           \
    const int q = QV;                                                         \
    const int k0 = ln * 4;                                                    \
    const int cbase = q * 1024 + k0;                                          \
    const f16x4 ef0 = *(const f16x4*)&sch[swz(q, k0 + 0)];                    \
    const f16x4 ef1 = *(const f16x4*)&sch[swz(q, k0 + 256)];                  \
    const f16x4 ef2 = *(const f16x4*)&sch[swz(q, k0 + 512)];                  \
    const f16x4 ef3 = *(const f16x4*)&sch[swz(q, k0 + 768)];                  \
    const f16x4 cb0 = *(const f16x4*)&comb[cbase + 0];                        \
    const f16x4 cb1 = *(const f16x4*)&comb[cbase + 256];                      \
    const f16x4 cb2 = *(const f16x4*)&comb[cbase + 512];                      \
    const f16x4 cb3 = *(const f16x4*)&comb[cbase + 768];                      \
    float s1 = 0.f;                                                           \
    _Pragma("unroll") for (int j = 0; j < 4; ++j) {                           \
      s1 += ((float)cb0[j] > -500.f ? (float)ef0[j] : 0.f);                   \
      s1 += ((float)cb1[j] > -500.f ? (float)ef1[j] : 0.f);                   \
      s1 += ((float)cb2[j] > -500.f ? (float)ef2[j] : 0.f);                   \
      s1 += ((float)cb3[j] > -500.f ? (float)ef3[j] : 0.f);                   \
    }                                                                         \
    s1 = wred(s1);                                                            \
    const float W0i = w0 * LOG2E / s1;                                        \
    f16x4 af0, af1, af2, af3;                                                 \
    float s2 = 0.f;                                                           \
    _Pragma("unroll") for (int j = 0; j < 4; ++j) {                           \
      const float a0 = exp2f(fmaf(W0i, (float)ef0[j], (float)cb0[j]));        \
      const float a1 = exp2f(fmaf(W0i, (float)ef1[j], (float)cb1[j]));        \
      const float a2 = exp2f(fmaf(W0i, (float)ef2[j], (float)cb2[j]));        \
      const float a3 = exp2f(fmaf(W0i, (float)ef3[j], (float)cb3[j]));        \
      af0[j] = (f16)a0; af1[j] = (f16)a1; af2[j] = (f16)a2; af3[j] = (f16)a3; \
      s2 += a0 + a1 + a2 + a3;                                                \
    }                                                                         \
    *(f16x4*)&sch[swz(q, k0 + 0)]   = af0;                                    \
    *(f16x4*)&sch[swz(q, k0 + 256)] = af1;                                    \
    *(f16x4*)&sch[swz(q, k0 + 512)] = af2;                                    \
    *(f16x4*)&sch[swz(q, k0 + 768)] = af3;                                    \
    s2 = wred(s2);                                                            \
    I2OUT = 1.f / s2;                                                         \
    const size_t base = rb + (size_t)q * S_;                                  \
    f32x4 o;                                                                  \
    o[0] = (float)af0[0] * I2OUT; o[1] = (float)af0[1] * I2OUT;               \
    o[2] = (float)af0[2] * I2OUT; o[3] = (float)af0[3] * I2OUT;               \
    __builtin_nontemporal_store(o, (f32x4*)(outA + base + k0 + 0));           \
    o[0] = (float)af1[0] * I2OUT; o[1] = (float)af1[1] * I2OUT;               \
    o[2] = (float)af1[2] * I2OUT; o[3] = (float)af1[3] * I2OUT;               \
    __builtin_nontemporal_store(o, (f32x4*)(outA + base + k0 + 256));         \
    o[0] = (float)af2[0] * I2OUT; o[1] = (float)af2[1] * I2OUT;               \
    o[2] = (float)af2[2] * I2OUT; o[3] = (float)af2[3] * I2OUT;               \
    __builtin_nontemporal_store(o, (f32x4*)(outA + base + k0 + 512));         \
    o[0] = (float)af3[0] * I2OUT; o[1] = (float)af3[1] * I2OUT;               \
    o[2] = (float)af3[2] * I2OUT; o[3] = (float)af3[3] * I2OUT;               \
    __builtin_nontemporal_store(o, (f32x4*)(outA + base + k0 + 768));         \
  }
  PHASEB(2 * wv, i2q0)
  PHASEB(2 * wv + 1, i2q1)
#undef PHASEB
  __syncthreads();                                  // (2) sch aw-values visible

  // ===== Phase C: ctx = P(f16) x V(f16); V^T fragments straight from global ==
  const int ntile = wv >> 1;
  const int spair = (wv & 1) * 2;
  const int d0 = ntile * 16 + li;
  f32x4 cacc = {0.f, 0.f, 0.f, 0.f};
#pragma unroll 2
  for (int c = 0; c < 8; ++c) {
#pragma unroll
    for (int u = 0; u < 2; ++u) {
      const int s = spair + u;
      const float* Vc = Vp + (size_t)(c * KC + s * 32 + lg * 8) * D_ + d0;
      f16x8 bfr;
#pragma unroll
      for (int j = 0; j < 8; ++j) bfr[j] = (f16)Vc[(size_t)j * D_];
      f16x8 a = *(const f16x8*)&sch[swz(li, c * KC + s * 32 + lg * 8)];
      cacc = __builtin_amdgcn_mfma_f32_16x16x32_f16(a, bfr, cacc, 0, 0, 0);
    }
  }
  __syncthreads();                                  // (3) all sch/comb reads done
  float* fscr = reinterpret_cast<float*>(sch);      // 8 KB scratch alias
  float* rinv = reinterpret_cast<float*>(comb);     // 64 B alias
  *(f32x4*)&fscr[tid * 4] = cacc;
  if (ln == 0) { rinv[2 * wv] = i2q0; rinv[2 * wv + 1] = i2q1; }
  __syncthreads();                                  // (4)
  if (tid < 256) {                    // combine wave pairs, scale, write ctx
    const int t = tid >> 6, l2 = tid & 63;
    const int g2 = l2 >> 4, n = l2 & 15;
    f32x4 p  = *(const f32x4*)&fscr[((2 * t) * 64 + l2) * 4];
    f32x4 p2 = *(const f32x4*)&fscr[((2 * t + 1) * 64 + l2) * 4];
#pragma unroll
    for (int r = 0; r < 4; ++r) {
      const int m = g2 * 4 + r;
      outC[((size_t)bh * S_ + q0 + m) * D_ + t * 16 + n] = (p[r] + p2[r]) * rinv[m];
    }
  }
}

extern "C" void kernel_launch(void* const* d_in, const int* in_sizes, int n_in,
                              void* d_out, int out_size, void* d_ws, size_t ws_size,
                              hipStream_t stream) {
  const float* Q    = (const float*)d_in[0];
  const float* K    = (const float*)d_in[1];
  const float* V    = (const float*)d_in[2];
  const int*   mask = (const int*)  d_in[3];
  const float* adj  = (const float*)d_in[4];
  const float* dist = (const float*)d_in[5];
  const float* cw   = (const float*)d_in[6];
  const float* cb   = (const float*)d_in[7];

  float* outC = (float*)d_out;                                   // [B,H,S,D]
  float* outA = outC + (size_t)B_ * H_ * S_ * D_;                // [B,H,S,S]

  fused_attn<<<dim3(B_ * H_ * (S_ / BQ)), NT, 0, stream>>>(
      Q, K, V, mask, adj, dist, cw, cb, outC, outA);
}

// Round 17
// 144.950 us; speedup vs baseline: 1.1223x; 1.0572x over previous
//
#include <hip/hip_runtime.h>

// Fused double-softmax attention, fp32 in/out, f16 MFMA for QK^T and PV.
// B=4 H=8 S=1024 D=64. Outputs: context [B,H,S,D] then attn [B,H,S,S].
// R17 = R13 + depth-2 issue-early/compute-late pipelines in Phase A (K frags)
// and Phase C (V frags): named double-buffer regs + sched_barrier(0) after
// each load-issue batch (m214-r277 pattern) to force loads into flight.
typedef _Float16 f16;
typedef _Float16 f16x8 __attribute__((ext_vector_type(8)));
typedef _Float16 f16x4 __attribute__((ext_vector_type(4)));
typedef float f32x4 __attribute__((ext_vector_type(4)));
typedef int   i32x4 __attribute__((ext_vector_type(4)));

constexpr int B_ = 4, H_ = 8, S_ = 1024, D_ = 64;
constexpr int BQ = 16;        // q rows per block
constexpr int NT = 512;       // 8 waves
constexpr int KC = 128;       // k per chunk (one 16-col tile per wave)
constexpr int QH_LD = 72;     // Qh row stride in f16
constexpr int SC_LD = 1032;   // sch row stride in f16
constexpr float LOG2E = 1.44269504f;

__device__ __forceinline__ float wred(float v) {
#pragma unroll
  for (int off = 32; off > 0; off >>= 1) v += __shfl_xor(v, off);
  return v;
}

#define PACK8(DST, X0, X1)                                                    \
  DST[0] = (f16)X0.x; DST[1] = (f16)X0.y; DST[2] = (f16)X0.z; DST[3] = (f16)X0.w; \
  DST[4] = (f16)X1.x; DST[5] = (f16)X1.y; DST[6] = (f16)X1.z; DST[7] = (f16)X1.w;

__global__ __launch_bounds__(NT)
void fused_attn(const float* __restrict__ Q, const float* __restrict__ K,
                const float* __restrict__ V, const int* __restrict__ mask,
                const float* __restrict__ adj, const float* __restrict__ dist,
                const float* __restrict__ cw, const float* __restrict__ cb,
                float* __restrict__ outC, float* __restrict__ outA)
{
  __shared__ __align__(16) f16 Qh[BQ * QH_LD];     // 2.3 KB
  __shared__ __align__(16) f16 sch[BQ * SC_LD];    // 33.0 KB (C-scratch reuse)
  __shared__ float rs1w[8][16];
  __shared__ float rinv2[BQ];

  const int tid = threadIdx.x;
  // bijective XCD swizzle: 2048 blocks = 8 XCDs x 256 (4 heads per XCD)
  const int sw = (blockIdx.x & 7) * 256 + (blockIdx.x >> 3);
  const int qt = sw & 63;
  const int bh = sw >> 6;
  const int q0 = qt * BQ;
  const int wv = tid >> 6;    // wave 0..7
  const int ln = tid & 63;
  const int lg = ln >> 4;     // lane group 0..3
  const int li = ln & 15;

  const float* Qp = Q + ((size_t)bh * S_ + q0) * D_;
  const float* Kp = K + (size_t)bh * S_ * D_;
  const float* Vp = V + (size_t)bh * S_ * D_;
  const size_t rb = ((size_t)bh * S_ + q0) * S_;

  // stage Q tile -> f16
  if (tid < 256) {
    const int q = tid >> 4, c4 = (tid & 15) << 2;
    float4 v = *(const float4*)(Qp + q * D_ + c4);
    f16* d = &Qh[q * QH_LD + c4];
    d[0] = (f16)v.x; d[1] = (f16)v.y; d[2] = (f16)v.z; d[3] = (f16)v.w;
  }
  const float w0 = cw[0], w1 = cw[1], w2 = cw[2], bb = cb[0];
  __syncthreads();                                  // (1)

  // hoist Q fragments (A operand; lane li = q-row li, k = s*32 + lg*8)
  f16x8 aq0 = *(const f16x8*)&Qh[li * QH_LD + 0 * 32 + lg * 8];
  f16x8 aq1 = *(const f16x8*)&Qh[li * QH_LD + 1 * 32 + lg * 8];

  // ===== Phase A: depth-2 pipelined K fragments + MFMA + exp =================
  const int n0 = wv * 16;
  float rs[4] = {0.f, 0.f, 0.f, 0.f};
#define KADDR(c) (Kp + (size_t)((c) * KC + n0 + li) * D_ + lg * 8)
  float4 Ar0, Ar1, Ar2, Ar3, Br0, Br1, Br2, Br3;
  {
    const float* p = KADDR(0);
    Ar0 = *(const float4*)(p + 0);  Ar1 = *(const float4*)(p + 4);
    Ar2 = *(const float4*)(p + 32); Ar3 = *(const float4*)(p + 36);
  }
  {
    const float* p = KADDR(1);
    Br0 = *(const float4*)(p + 0);  Br1 = *(const float4*)(p + 4);
    Br2 = *(const float4*)(p + 32); Br3 = *(const float4*)(p + 36);
  }
#define ACHUNK(CC, R0, R1, R2, R3, PF)                                        \
  {                                                                           \
    f16x8 b0, b1;                                                             \
    PACK8(b0, R0, R1)                                                         \
    PACK8(b1, R2, R3)                                                         \
    if ((PF) < 8) {                                                           \
      const float* p = KADDR(PF);                                             \
      R0 = *(const float4*)(p + 0);  R1 = *(const float4*)(p + 4);            \
      R2 = *(const float4*)(p + 32); R3 = *(const float4*)(p + 36);           \
    }                                                                         \
    __builtin_amdgcn_sched_barrier(0);                                        \
    f32x4 acc = {0.f, 0.f, 0.f, 0.f};                                         \
    acc = __builtin_amdgcn_mfma_f32_16x16x32_f16(aq0, b0, acc, 0, 0, 0);      \
    acc = __builtin_amdgcn_mfma_f32_16x16x32_f16(aq1, b1, acc, 0, 0, 0);      \
    const int kg = (CC) * KC + n0 + li;                                       \
    _Pragma("unroll") for (int r = 0; r < 4; ++r) {                           \
      const int m = lg * 4 + r;                                               \
      const f16 ef = (f16)exp2f(acc[r] * (0.125f * LOG2E));                   \
      sch[m * SC_LD + kg] = ef;                                               \
      rs[r] += (float)ef;                                                     \
    }                                                                         \
  }
#pragma unroll
  for (int c = 0; c < 8; c += 2) {
    ACHUNK(c,     Ar0, Ar1, Ar2, Ar3, c + 2)
    ACHUNK(c + 1, Br0, Br1, Br2, Br3, c + 3)
  }
#undef ACHUNK
#undef KADDR
#pragma unroll
  for (int r = 0; r < 4; ++r) {              // reduce over 16 lanes per group
    rs[r] += __shfl_xor(rs[r], 1); rs[r] += __shfl_xor(rs[r], 2);
    rs[r] += __shfl_xor(rs[r], 4); rs[r] += __shfl_xor(rs[r], 8);
  }
  if (li == 0) {
#pragma unroll
    for (int r = 0; r < 4; ++r) rs1w[wv][lg * 4 + r] = rs[r];
  }
  __syncthreads();                                  // (2) sch + rs1w visible

  // ===== Phase B: mask fold + conv-softmax; wave -> rows 2wv, 2wv+1 ==========
#pragma unroll
  for (int rr = 0; rr < 2; ++rr) {
    const int q = 2 * wv + rr;
    const size_t base = rb + (size_t)q * S_;
    const int k0 = ln * 4;
    // batched NONTEMPORAL loads: 12 global + 4 LDS issued before any use
    const i32x4 mv0 = __builtin_nontemporal_load((const i32x4*)(mask + base + k0 + 0));
    const i32x4 mv1 = __builtin_nontemporal_load((const i32x4*)(mask + base + k0 + 256));
    const i32x4 mv2 = __builtin_nontemporal_load((const i32x4*)(mask + base + k0 + 512));
    const i32x4 mv3 = __builtin_nontemporal_load((const i32x4*)(mask + base + k0 + 768));
    const f32x4 dv0 = __builtin_nontemporal_load((const f32x4*)(dist + base + k0 + 0));
    const f32x4 dv1 = __builtin_nontemporal_load((const f32x4*)(dist + base + k0 + 256));
    const f32x4 dv2 = __builtin_nontemporal_load((const f32x4*)(dist + base + k0 + 512));
    const f32x4 dv3 = __builtin_nontemporal_load((const f32x4*)(dist + base + k0 + 768));
    const f32x4 av0 = __builtin_nontemporal_load((const f32x4*)(adj + base + k0 + 0));
    const f32x4 av1 = __builtin_nontemporal_load((const f32x4*)(adj + base + k0 + 256));
    const f32x4 av2 = __builtin_nontemporal_load((const f32x4*)(adj + base + k0 + 512));
    const f32x4 av3 = __builtin_nontemporal_load((const f32x4*)(adj + base + k0 + 768));
    const f16x4 ef0 = *(const f16x4*)&sch[q * SC_LD + k0 + 0];
    const f16x4 ef1 = *(const f16x4*)&sch[q * SC_LD + k0 + 256];
    const f16x4 ef2 = *(const f16x4*)&sch[q * SC_LD + k0 + 512];
    const f16x4 ef3 = *(const f16x4*)&sch[q * SC_LD + k0 + 768];
    __builtin_amdgcn_sched_barrier(0);
    // denominator correction from masked entries
    float corr =
        (mv0[0] ? (float)ef0[0] : 0.f) + (mv0[1] ? (float)ef0[1] : 0.f) +
        (mv0[2] ? (float)ef0[2] : 0.f) + (mv0[3] ? (float)ef0[3] : 0.f) +
        (mv1[0] ? (float)ef1[0] : 0.f) + (mv1[1] ? (float)ef1[1] : 0.f) +
        (mv1[2] ? (float)ef1[2] : 0.f) + (mv1[3] ? (float)ef1[3] : 0.f) +
        (mv2[0] ? (float)ef2[0] : 0.f) + (mv2[1] ? (float)ef2[1] : 0.f) +
        (mv2[2] ? (float)ef2[2] : 0.f) + (mv2[3] ? (float)ef2[3] : 0.f) +
        (mv3[0] ? (float)ef3[0] : 0.f) + (mv3[1] ? (float)ef3[1] : 0.f) +
        (mv3[2] ? (float)ef3[2] : 0.f) + (mv3[3] ? (float)ef3[3] : 0.f);
    float tq = 0.f;
#pragma unroll
    for (int w = 0; w < 8; ++w) tq += rs1w[w][q];   // uniform broadcast reads
    corr = wred(corr);
    const float i1 = 1.f / (tq - corr);
    const float W0 = w0 * i1 * LOG2E, W1 = w1 * LOG2E, W2 = w2 * LOG2E;
    const float BBL = bb * LOG2E;
    f16x4 af0, af1, af2, af3;
    float s2 = 0.f;
#define CSM(AF, MV, DV, AV, EF)                                               \
    {                                                                         \
      const float t0 = fmaf(W0, (float)EF[0], fmaf(W1, DV[0], fmaf(W2, AV[0], BBL))); \
      const float t1 = fmaf(W0, (float)EF[1], fmaf(W1, DV[1], fmaf(W2, AV[1], BBL))); \
      const float t2 = fmaf(W0, (float)EF[2], fmaf(W1, DV[2], fmaf(W2, AV[2], BBL))); \
      const float t3 = fmaf(W0, (float)EF[3], fmaf(W1, DV[3], fmaf(W2, AV[3], BBL))); \
      const float a0 = MV[0] ? 0.f : exp2f(t0);                               \
      const float a1 = MV[1] ? 0.f : exp2f(t1);                               \
      const float a2 = MV[2] ? 0.f : exp2f(t2);                               \
      const float a3 = MV[3] ? 0.f : exp2f(t3);                               \
      AF[0] = (f16)a0; AF[1] = (f16)a1; AF[2] = (f16)a2; AF[3] = (f16)a3;     \
      s2 += a0 + a1 + a2 + a3;                                                \
    }
    CSM(af0, mv0, dv0, av0, ef0)
    CSM(af1, mv1, dv1, av1, ef1)
    CSM(af2, mv2, dv2, av2, ef2)
    CSM(af3, mv3, dv3, av3, ef3)
#undef CSM
    *(f16x4*)&sch[q * SC_LD + k0 + 0]   = af0;
    *(f16x4*)&sch[q * SC_LD + k0 + 256] = af1;
    *(f16x4*)&sch[q * SC_LD + k0 + 512] = af2;
    *(f16x4*)&sch[q * SC_LD + k0 + 768] = af3;
    s2 = wred(s2);
    const float i2 = 1.f / s2;
    if (ln == 0) rinv2[q] = i2;
    f32x4 o;
    o[0] = (float)af0[0] * i2; o[1] = (float)af0[1] * i2;
    o[2] = (float)af0[2] * i2; o[3] = (float)af0[3] * i2;
    __builtin_nontemporal_store(o, (f32x4*)(outA + base + k0 + 0));
    o[0] = (float)af1[0] * i2; o[1] = (float)af1[1] * i2;
    o[2] = (float)af1[2] * i2; o[3] = (float)af1[3] * i2;
    __builtin_nontemporal_store(o, (f32x4*)(outA + base + k0 + 256));
    o[0] = (float)af2[0] * i2; o[1] = (float)af2[1] * i2;
    o[2] = (float)af2[2] * i2; o[3] = (float)af2[3] * i2;
    __builtin_nontemporal_store(o, (f32x4*)(outA + base + k0 + 512));
    o[0] = (float)af3[0] * i2; o[1] = (float)af3[1] * i2;
    o[2] = (float)af3[2] * i2; o[3] = (float)af3[3] * i2;
    __builtin_nontemporal_store(o, (f32x4*)(outA + base + k0 + 768));
  }
  __syncthreads();                                  // (3) sch aw-values visible

  // ===== Phase C: depth-2 pipelined V^T fragments + MFMA =====================
  const int ntile = wv >> 1;
  const int spair = (wv & 1) * 2;
  const int d0 = ntile * 16 + li;
#define VADDR(T) (Vp + (size_t)((((T) >> 1)) * KC + (spair + ((T) & 1)) * 32 + lg * 8) * D_ + d0)
  f32x4 cacc = {0.f, 0.f, 0.f, 0.f};
  float vA0, vA1, vA2, vA3, vA4, vA5, vA6, vA7;
  float vB0, vB1, vB2, vB3, vB4, vB5, vB6, vB7;
  {
    const float* p = VADDR(0);
    vA0 = p[0 * D_]; vA1 = p[1 * D_]; vA2 = p[2 * D_]; vA3 = p[3 * D_];
    vA4 = p[4 * D_]; vA5 = p[5 * D_]; vA6 = p[6 * D_]; vA7 = p[7 * D_];
  }
  {
    const float* p = VADDR(1);
    vB0 = p[0 * D_]; vB1 = p[1 * D_]; vB2 = p[2 * D_]; vB3 = p[3 * D_];
    vB4 = p[4 * D_]; vB5 = p[5 * D_]; vB6 = p[6 * D_]; vB7 = p[7 * D_];
  }
#define CSTEP(T, V0, V1, V2, V3, V4, V5, V6, V7, PF)                          \
  {                                                                           \
    f16x8 bfr;                                                                \
    bfr[0] = (f16)V0; bfr[1] = (f16)V1; bfr[2] = (f16)V2; bfr[3] = (f16)V3;   \
    bfr[4] = (f16)V4; bfr[5] = (f16)V5; bfr[6] = (f16)V6; bfr[7] = (f16)V7;   \
    if ((PF) < 16) {                                                          \
      const float* p = VADDR(PF);                                             \
      V0 = p[0 * D_]; V1 = p[1 * D_]; V2 = p[2 * D_]; V3 = p[3 * D_];         \
      V4 = p[4 * D_]; V5 = p[5 * D_]; V6 = p[6 * D_]; V7 = p[7 * D_];         \
    }                                                                         \
    __builtin_amdgcn_sched_barrier(0);                                        \
    const int cc = (T) >> 1, uu = (T) & 1;                                    \
    f16x8 a = *(const f16x8*)&sch[li * SC_LD + cc * KC + (spair + uu) * 32 + lg * 8]; \
    cacc = __builtin_amdgcn_mfma_f32_16x16x32_f16(a, bfr, cacc, 0, 0, 0);     \
  }
#pragma unroll
  for (int t = 0; t < 16; t += 2) {
    CSTEP(t,     vA0, vA1, vA2, vA3, vA4, vA5, vA6, vA7, t + 2)
    CSTEP(t + 1, vB0, vB1, vB2, vB3, vB4, vB5, vB6, vB7, t + 3)
  }
#undef CSTEP
#undef VADDR
  __syncthreads();                                  // (4) all sch reads done
  float* fscr = reinterpret_cast<float*>(sch);      // alias 8 KB scratch
  *(f32x4*)&fscr[tid * 4] = cacc;
  __syncthreads();                                  // (5)
  if (tid < 256) {                    // combine wave pairs, scale, write ctx
    const int t = tid >> 6, l2 = tid & 63;
    const int g2 = l2 >> 4, n = l2 & 15;
    f32x4 p  = *(const f32x4*)&fscr[((2 * t) * 64 + l2) * 4];
    f32x4 p2 = *(const f32x4*)&fscr[((2 * t + 1) * 64 + l2) * 4];
#pragma unroll
    for (int r = 0; r < 4; ++r) {
      const int m = g2 * 4 + r;
      outC[((size_t)bh * S_ + q0 + m) * D_ + t * 16 + n] = (p[r] + p2[r]) * rinv2[m];
    }
  }
}

extern "C" void kernel_launch(void* const* d_in, const int* in_sizes, int n_in,
                              void* d_out, int out_size, void* d_ws, size_t ws_size,
                              hipStream_t stream) {
  const float* Q    = (const float*)d_in[0];
  const float* K    = (const float*)d_in[1];
  const float* V    = (const float*)d_in[2];
  const int*   mask = (const int*)  d_in[3];
  const float* adj  = (const float*)d_in[4];
  const float* dist = (const float*)d_in[5];
  const float* cw   = (const float*)d_in[6];
  const float* cb   = (const float*)d_in[7];

  float* outC = (float*)d_out;                                   // [B,H,S,D]
  float* outA = outC + (size_t)B_ * H_ * S_ * D_;                // [B,H,S,S]

  fused_attn<<<dim3(B_ * H_ * (S_ / BQ)), NT, 0, stream>>>(
      Q, K, V, mask, adj, dist, cw, cb, outC, outA);
}